// Round 10
// baseline (2231.857 us; speedup 1.0000x reference)
//
#include <hip/hip_runtime.h>
#include <stdint.h>

typedef int v4i __attribute__((ext_vector_type(4)));
typedef int v8i __attribute__((ext_vector_type(8)));
typedef float v4f __attribute__((ext_vector_type(4)));
typedef short v8s __attribute__((ext_vector_type(8)));
typedef unsigned long long ull;
typedef unsigned int uint;

#define GLOAD16(g, l)                                                          \
  __builtin_amdgcn_global_load_lds(                                            \
      (const __attribute__((address_space(1))) void*)(g),                      \
      (__attribute__((address_space(3))) void*)(l), 16, 0, 0)

__device__ __forceinline__ void bar() {
  asm volatile("" ::: "memory");
  __builtin_amdgcn_s_barrier();
  asm volatile("" ::: "memory");
}

__device__ __forceinline__ signed char sgnf(float v) {
  return v > 0.f ? (signed char)1 : (v < 0.f ? (signed char)-1 : (signed char)0);
}
// fp4 e2m1 codes: +1.0 = 0x2, -1.0 = 0xA, 0.0 = 0x0
__device__ __forceinline__ uint nib(float v) {
  return v > 0.f ? 2u : (v < 0.f ? 10u : 0u);
}

// ---------------- binarize fp32 -> i8 sign (tiny weights only) ----------------
__global__ void k_bin(const float4* __restrict__ in, char4* __restrict__ out, int n4) {
  int i = blockIdx.x * blockDim.x + threadIdx.x;
  int stride = gridDim.x * blockDim.x;
  for (; i < n4; i += stride) {
    float4 v = in[i];
    char4 o;
    o.x = sgnf(v.x); o.y = sgnf(v.y); o.z = sgnf(v.z); o.w = sgnf(v.w);
    out[i] = o;
  }
}

// ---------------- binarize fp32 -> packed fp4 (2 elems/byte) ----------------
__global__ void k_binp(const float4* __restrict__ in, uint* __restrict__ out, int n8) {
  int i = blockIdx.x * blockDim.x + threadIdx.x;
  int stride = gridDim.x * blockDim.x;
  for (; i < n8; i += stride) {
    float4 a = in[i * 2], b = in[i * 2 + 1];
    out[i] = nib(a.x) | (nib(a.y) << 4) | (nib(a.z) << 8) | (nib(a.w) << 12) |
             (nib(b.x) << 16) | (nib(b.y) << 20) | (nib(b.z) << 24) | (nib(b.w) << 28);
  }
}

// ======== 256x256 4-phase counted-vmcnt MX-fp4 GEMM — R7 ledger, R9 reg budget ====
// 512 thr = 8 waves (2Mx4N); per-wave C 128x64. LDS 2x(A32K+B32K). 16x16x128 shape.
// Phases (0,0),(0,1),(1,0),(1,1) — R7's HW-verified order. Persist a8[4][2]+b8[2][2];
// re-read B0@ph3, B1@ph4. Staging: ph1 A1(t+1)->q, ph2 B1(t+1)->q,
// ph4 B0(t+2)+A0(t+2)->p (issued AFTER every read of those regions completed:
// A0 last read ph3 RDA(1) wm=0 rows 64-127; B0 last read ph3 re-read — both
// barrier-separated from ph4). vmcnt(4)@ph4 drains exactly tile t+1's 8 loads
// (steady-state outstanding = 12). Epilogue vmcnt(0) at t >= NT-2.
// R9's race (curbuf staging at ph2/ph3 before那 region's last read) is removed.
template <int K, int N>
__global__ __launch_bounds__(512, 1) void k_bgemm2(
    const unsigned char* __restrict__ X, const unsigned char* __restrict__ W,
    short* __restrict__ A, ull* __restrict__ S, int M)
{
  __shared__ __align__(16) unsigned char lds[2][2][32768];
  constexpr int Kb = K >> 1;
  constexpr int NT = K / 256;
  constexpr int NBX = N / 256;
  const int tid = threadIdx.x;
  const int lane = tid & 63;
  const int wave = tid >> 6;
  const int wm = wave >> 2, wn = wave & 3;
  const int wg = blockIdx.x;
  const int bm = (wg / NBX) * 256, bn = (wg % NBX) * 256;

  const int srow = lane >> 3;
  const int ssl = (lane & 7) ^ srow;       // inverse source swizzle
  const int l15 = lane & 15;
  const int q4 = lane >> 4;

  const unsigned char* Xb = X + (size_t)bm * Kb;
  const unsigned char* Wb = W + (size_t)bn * Kb;

  uint voff[2][2];
  uint ldst[2][2];
#pragma unroll
  for (int h = 0; h < 2; ++h)
#pragma unroll
    for (int c = 0; c < 2; ++c) {
      int row = h * 128 + c * 64 + wave * 8 + srow;
      voff[h][c] = (uint)(row * Kb + ssl * 16);
      ldst[h][c] = (uint)((h * 128 + c * 64 + wave * 8) * 128);
    }

#define STA(h, buf, tt) {                                                      \
    GLOAD16(Xb + voff[h][0] + (tt) * 128, &lds[buf][0][ldst[h][0]]);           \
    GLOAD16(Xb + voff[h][1] + (tt) * 128, &lds[buf][0][ldst[h][1]]); }
#define STB(h, buf, tt) {                                                      \
    GLOAD16(Wb + voff[h][0] + (tt) * 128, &lds[buf][1][ldst[h][0]]);           \
    GLOAD16(Wb + voff[h][1] + (tt) * 128, &lds[buf][1][ldst[h][1]]); }

  // ds_read bases: swizzle term is m-independent (16-row steps preserve row&7)
  const uint aswz = (uint)((q4 ^ (l15 & 7)) << 4);
  const uint a0 = (uint)((wm * 128 + l15) * 128) + aswz;
  const uint a1 = a0 ^ 64;
  const uint b0 = (uint)((wn * 64 + l15) * 128) + aswz;
  const uint b1 = b0 ^ 64;

  v4f acc[8][4] = {};
  v8i a8[4][2], b8[2][2];
#pragma unroll
  for (int i = 0; i < 4; ++i)
#pragma unroll
    for (int kk = 0; kk < 2; ++kk) a8[i][kk] = (v8i)(0);
#pragma unroll
  for (int i = 0; i < 2; ++i)
#pragma unroll
    for (int kk = 0; kk < 2; ++kk) b8[i][kk] = (v8i)(0);

#define RDA(mh, Ap)                                                            \
  _Pragma("unroll") for (int mq = 0; mq < 4; ++mq) {                           \
    v4i t0_ = *(const v4i*)((Ap) + a0 + (mh) * 8192 + mq * 2048);              \
    a8[mq][0][0] = t0_[0]; a8[mq][0][1] = t0_[1];                              \
    a8[mq][0][2] = t0_[2]; a8[mq][0][3] = t0_[3];                              \
    v4i t1_ = *(const v4i*)((Ap) + a1 + (mh) * 8192 + mq * 2048);              \
    a8[mq][1][0] = t1_[0]; a8[mq][1][1] = t1_[1];                              \
    a8[mq][1][2] = t1_[2]; a8[mq][1][3] = t1_[3]; }
#define RDB(nh, Bp)                                                            \
  _Pragma("unroll") for (int nq = 0; nq < 2; ++nq) {                           \
    v4i t0_ = *(const v4i*)((Bp) + b0 + (nh) * 4096 + nq * 2048);              \
    b8[nq][0][0] = t0_[0]; b8[nq][0][1] = t0_[1];                              \
    b8[nq][0][2] = t0_[2]; b8[nq][0][3] = t0_[3];                              \
    v4i t1_ = *(const v4i*)((Bp) + b1 + (nh) * 4096 + nq * 2048);              \
    b8[nq][1][0] = t1_[0]; b8[nq][1][1] = t1_[1];                              \
    b8[nq][1][2] = t1_[2]; b8[nq][1][3] = t1_[3]; }
#define PQUAD(mh, nh)                                                          \
  { __builtin_amdgcn_s_setprio(1);                                             \
    _Pragma("unroll") for (int mq = 0; mq < 4; ++mq)                           \
      _Pragma("unroll") for (int nq = 0; nq < 2; ++nq)                         \
        _Pragma("unroll") for (int kk = 0; kk < 2; ++kk)                       \
          acc[(mh) * 4 + mq][(nh) * 2 + nq] =                                  \
              __builtin_amdgcn_mfma_scale_f32_16x16x128_f8f6f4(                \
                  a8[mq][kk], b8[nq][kk], acc[(mh) * 4 + mq][(nh) * 2 + nq],   \
                  4, 4, 0, 0x7F7F7F7Fu, 0, 0x7F7F7F7Fu);                       \
    __builtin_amdgcn_s_setprio(0); }

  // prologue: tile0 all 4 halves (8 loads, oldest) + tile1 A0,B0 (4 loads)
  STA(0, 0, 0); STB(0, 0, 0); STA(1, 0, 0); STB(1, 0, 0);
  STA(0, 1, 1); STB(0, 1, 1);
  asm volatile("s_waitcnt vmcnt(4)" ::: "memory");
  bar();

#pragma unroll 2
  for (int t = 0; t < NT; ++t) {
    const int p = t & 1, qb = p ^ 1;
    const unsigned char* Ap = &lds[p][0][0];
    const unsigned char* Bp = &lds[p][1][0];
    // ph1 (0,0)
    RDA(0, Ap); RDB(0, Bp);
    if (t + 1 < NT) STA(1, qb, t + 1);
    bar(); PQUAD(0, 0); bar();
    // ph2 (0,1) — reuse A0, read B1
    RDB(1, Bp);
    if (t + 1 < NT) STB(1, qb, t + 1);
    bar(); PQUAD(0, 1); bar();
    // ph3 (1,0) — read A1, re-read B0
    RDA(1, Ap); RDB(0, Bp);
    bar(); PQUAD(1, 0); bar();
    // ph4 (1,1) — re-read B1; stage t+2 into p (all reads of those regions done)
    RDB(1, Bp);
    if (t + 2 < NT) {
      STB(0, p, t + 2); STA(0, p, t + 2);
      asm volatile("s_waitcnt vmcnt(4)" ::: "memory");
    } else {
      asm volatile("s_waitcnt vmcnt(0)" ::: "memory");
    }
    bar(); PQUAD(1, 1); bar();
  }
#undef RDA
#undef RDB
#undef PQUAD
#undef STA
#undef STB

  // C layout (verified): col = lane&15, row = (lane>>4)*4 + reg; nontemporal
#pragma unroll
  for (int m = 0; m < 8; ++m) {
    int rbase = bm + wm * 128 + m * 16 + q4 * 4;
#pragma unroll
    for (int n = 0; n < 4; ++n) {
      int col = bn + wn * 64 + n * 16 + l15;
#pragma unroll
      for (int r = 0; r < 4; ++r)
        __builtin_nontemporal_store((short)(int)acc[m][n][r],
                                    A + (size_t)(rbase + r) * N + col);
    }
  }

  // fused per-column stats (exact; sumsq in int64: 128*4096^2 > 2^31)
#pragma unroll
  for (int n = 0; n < 4; ++n) {
    int s = 0; long long q64 = 0;
#pragma unroll
    for (int m = 0; m < 8; ++m) {
      int qq = 0;
#pragma unroll
      for (int r = 0; r < 4; ++r) {
        int v = (int)acc[m][n][r];
        s += v; qq += v * v;
      }
      q64 += qq;
    }
    s += __shfl_xor(s, 16); s += __shfl_xor(s, 32);
    q64 += __shfl_xor(q64, 16); q64 += __shfl_xor(q64, 32);
    if (q4 == 0) {
      int col = bn + wn * 64 + n * 16 + l15;
      atomicAdd(&S[col], (ull)(long long)s);
      atomicAdd(&S[(size_t)N + col], (ull)q64);
    }
  }
}

// ---------------- 128x128 2-barrier 16x16x128 kernel (R6-verified; small-N L2) ----
#define BM 128
#define BN 128

template <int K, int N>
__global__ __launch_bounds__(256, 2) void k_bgemm(
    const unsigned char* __restrict__ X, const unsigned char* __restrict__ W,
    short* __restrict__ A, ull* __restrict__ S, int M)
{
  __shared__ __align__(16) unsigned char As[BM * 128];
  __shared__ __align__(16) unsigned char Bs[BN * 128];
  constexpr int Kb = K >> 1;
  constexpr int NT = K / 256;
  constexpr int NBX = N / BN;
  const int t = threadIdx.x;
  const int lane = t & 63;
  const int wave = t >> 6;
  const int wm = wave >> 1, wn = wave & 1;
  const int wg = blockIdx.x;             // natural order (R5: %8 partitions W)
  const int bm = (wg / NBX) * BM, bn = (wg % NBX) * BN;

  const int srow = lane >> 3;
  const int sslot = (lane & 7);

  const unsigned char* Xb0 = X + (size_t)bm * Kb;
  const unsigned char* Wb0 = W + (size_t)bn * Kb;

  v4f acc[4][4] = {};
  v8i a8[4], b8[4];
#pragma unroll
  for (int m = 0; m < 4; ++m) { a8[m] = (v8i)(0); b8[m] = (v8i)(0); }

  const unsigned char* gx[4];
  const unsigned char* gw[4];
  int ldsoff[4];
#pragma unroll
  for (int c = 0; c < 4; ++c) {
    int br = (wave * 4 + c) * 8;
    int row = br + srow;
    int ss = sslot ^ (row & 7);
    gx[c] = Xb0 + (size_t)row * Kb + ss * 16;
    gw[c] = Wb0 + (size_t)row * Kb + ss * 16;
    ldsoff[c] = br * 128;
  }
  int aoff[4], boff[4];
#pragma unroll
  for (int m = 0; m < 4; ++m) {
    int arow = wm * 64 + m * 16 + (lane & 15);
    aoff[m] = arow * 128 + (((lane >> 4) ^ (arow & 7)) * 16);
    int brow = wn * 64 + m * 16 + (lane & 15);
    boff[m] = brow * 128 + (((lane >> 4) ^ (brow & 7)) * 16);
  }

#pragma unroll
  for (int tile = 0; tile < NT; ++tile) {
#pragma unroll
    for (int c = 0; c < 4; ++c) {
      GLOAD16(gx[c] + tile * 128, As + ldsoff[c]);
      GLOAD16(gw[c] + tile * 128, Bs + ldsoff[c]);
    }
    __syncthreads();
#pragma unroll
    for (int kk = 0; kk < 2; ++kk) {
#pragma unroll
      for (int m = 0; m < 4; ++m) {
        v4i tmp = *(const v4i*)(As + (aoff[m] ^ (kk << 6)));
        a8[m][0] = tmp[0]; a8[m][1] = tmp[1]; a8[m][2] = tmp[2]; a8[m][3] = tmp[3];
      }
#pragma unroll
      for (int n = 0; n < 4; ++n) {
        v4i tmp = *(const v4i*)(Bs + (boff[n] ^ (kk << 6)));
        b8[n][0] = tmp[0]; b8[n][1] = tmp[1]; b8[n][2] = tmp[2]; b8[n][3] = tmp[3];
      }
#pragma unroll
      for (int m = 0; m < 4; ++m)
#pragma unroll
        for (int n = 0; n < 4; ++n)
          acc[m][n] = __builtin_amdgcn_mfma_scale_f32_16x16x128_f8f6f4(
              a8[m], b8[n], acc[m][n], 4, 4, 0, 0x7F7F7F7Fu, 0, 0x7F7F7F7Fu);
    }
    __syncthreads();
  }

#pragma unroll
  for (int m = 0; m < 4; ++m) {
    int rbase = bm + wm * 64 + m * 16 + (lane >> 4) * 4;
#pragma unroll
    for (int n = 0; n < 4; ++n) {
      int col = bn + wn * 64 + n * 16 + (lane & 15);
#pragma unroll
      for (int r = 0; r < 4; ++r)
        __builtin_nontemporal_store((short)(int)acc[m][n][r],
                                    A + (size_t)(rbase + r) * N + col);
    }
  }

#pragma unroll
  for (int n = 0; n < 4; ++n) {
    int s = 0, q = 0;
#pragma unroll
    for (int m = 0; m < 4; ++m)
#pragma unroll
      for (int r = 0; r < 4; ++r) {
        int v = (int)acc[m][n][r];
        s += v; q += v * v;
      }
    s += __shfl_xor(s, 16); s += __shfl_xor(s, 32);
    q += __shfl_xor(q, 16); q += __shfl_xor(q, 32);
    if ((lane >> 4) == 0) {
      int col = bn + wn * 64 + n * 16 + (lane & 15);
      atomicAdd(&S[col], (ull)(long long)s);
      atomicAdd(&S[(size_t)N + col], (ull)(long long)q);
    }
  }
}

// ---------------- stats -> (mean, g*rsqrt(var+eps)) per column ----------------
__global__ void k_finalize(const ull* __restrict__ sums, const float* __restrict__ g,
                           int M, int N, float* __restrict__ meanf, float* __restrict__ sgf) {
  int j = blockIdx.x * blockDim.x + threadIdx.x;
  if (j >= N) return;
  double sum = (double)(long long)sums[j];
  double sumsq = (double)(long long)sums[N + j];
  double mean = sum / (double)M;
  double var = sumsq / (double)M - mean * mean;
  if (var < 0.0) var = 0.0;
  double inv = 1.0 / sqrt(var + 1e-5);
  meanf[j] = (float)mean;
  sgf[j] = (float)(inv * (double)g[j]);
}

// ---------------- sign(batchnorm(a)) -> packed fp4 (bias cancels under BN) ----
__global__ void k_signbn_pack(const short* __restrict__ A, const float* __restrict__ meanf,
                              const float* __restrict__ sgf, const float* __restrict__ be,
                              uint* __restrict__ Xp, int total8, int nmask) {
  int i = blockIdx.x * blockDim.x + threadIdx.x;
  int stride = gridDim.x * blockDim.x;
  for (; i < total8; i += stride) {
    v8s a = __builtin_nontemporal_load((const v8s*)(A + (size_t)i * 8));
    int c0 = (i * 8) & nmask;
    uint b = 0;
#pragma unroll
    for (int j = 0; j < 8; ++j) {
      float z = ((float)a[j] - meanf[c0 + j]) * sgf[c0 + j] + be[c0 + j];
      b |= nib(z) << (4 * j);
    }
    Xp[i] = b;
  }
}

// ---------------- sign(batchnorm(a)) -> i8 (for the tail) ----------------
__global__ void k_signbn(const short4* __restrict__ A4, const float* __restrict__ meanf,
                         const float* __restrict__ sgf, const float* __restrict__ be,
                         char4* __restrict__ X4, int total4, int nmask) {
  int i = blockIdx.x * blockDim.x + threadIdx.x;
  int stride = gridDim.x * blockDim.x;
  for (; i < total4; i += stride) {
    short4 a = A4[i];
    int c0 = (i * 4) & nmask;
    char4 o;
    o.x = sgnf(((float)a.x - meanf[c0    ]) * sgf[c0    ] + be[c0    ]);
    o.y = sgnf(((float)a.y - meanf[c0 + 1]) * sgf[c0 + 1] + be[c0 + 1]);
    o.z = sgnf(((float)a.z - meanf[c0 + 2]) * sgf[c0 + 2] + be[c0 + 2]);
    o.w = sgnf(((float)a.w - meanf[c0 + 3]) * sgf[c0 + 3] + be[c0 + 3]);
    X4[i] = o;
  }
}

// ---------------- fused layers 3,4,5: X3[M,256] -> A5[M,10] + stats ----------------
__global__ __launch_bounds__(256) void k_tail(
    const signed char* __restrict__ X3, const signed char* __restrict__ W3,
    const signed char* __restrict__ W4, const signed char* __restrict__ W5,
    const float* __restrict__ b3, const float* __restrict__ b4,
    int* __restrict__ A5, ull* __restrict__ sums5, int M)
{
  __shared__ __align__(16) signed char sW3[16 * 256];
  __shared__ __align__(16) signed char sW4[256];
  __shared__ __align__(16) signed char sW5[160];
  __shared__ __align__(16) signed char sX[16 * 256];
  __shared__ signed char sH[16][16];
  __shared__ int bsum[10], bsq[10];
  int t = threadIdx.x;
  int rowBlock = blockIdx.x * 16;
  ((int4*)sW3)[t] = ((const int4*)W3)[t];
  ((int4*)sX)[t] = ((const int4*)(X3 + (size_t)rowBlock * 256))[t];
  if (t < 16) ((int4*)sW4)[t] = ((const int4*)W4)[t];
  if (t < 10) {
    ((int4*)sW5)[t] = ((const int4*)W5)[t];
    bsum[t] = 0; bsq[t] = 0;
  }
  __syncthreads();
  int r = t >> 4, j = t & 15;
  int d3 = 0;
#pragma unroll 8
  for (int k = 0; k < 256; ++k) d3 += (int)sX[r * 256 + k] * (int)sW3[j * 256 + k];
  sH[r][j] = sgnf((float)d3 + b3[j]);   // sign(hardtanh(z)) == sign(z)
  __syncthreads();
  int d4 = 0;
#pragma unroll
  for (int k = 0; k < 16; ++k) d4 += (int)sH[r][k] * (int)sW4[j * 16 + k];
  signed char x5 = sgnf((float)d4 + b4[j]);
  __syncthreads();
  sH[r][j] = x5;
  __syncthreads();
  if (j < 10) {
    int d5 = 0;
#pragma unroll
    for (int k = 0; k < 16; ++k) d5 += (int)sH[r][k] * (int)sW5[j * 16 + k];
    A5[(size_t)(rowBlock + r) * 10 + j] = d5;
    atomicAdd(&bsum[j], d5);
    atomicAdd(&bsq[j], d5 * d5);
  }
  __syncthreads();
  if (t < 10) {
    atomicAdd(&sums5[t], (ull)(long long)bsum[t]);
    atomicAdd(&sums5[10 + t], (ull)(long long)bsq[t]);
  }
}

// ---------------- final BN + log_softmax ----------------
__global__ void k_lsm(const int* __restrict__ A5, const float* __restrict__ meanf,
                      const float* __restrict__ sgf, const float* __restrict__ be,
                      float* __restrict__ out, int M) {
  int r = blockIdx.x * blockDim.x + threadIdx.x;
  if (r >= M) return;
  float tv[10]; float mx = -3.0e38f;
#pragma unroll
  for (int j = 0; j < 10; ++j) {
    tv[j] = ((float)A5[(size_t)r * 10 + j] - meanf[j]) * sgf[j] + be[j];
    mx = fmaxf(mx, tv[j]);
  }
  float s = 0.f;
#pragma unroll
  for (int j = 0; j < 10; ++j) s += expf(tv[j] - mx);
  float lse = mx + logf(s);
#pragma unroll
  for (int j = 0; j < 10; ++j) out[(size_t)r * 10 + j] = tv[j] - lse;
}

extern "C" void kernel_launch(void* const* d_in, const int* in_sizes, int n_in,
                              void* d_out, int out_size, void* d_ws, size_t ws_size,
                              hipStream_t stream) {
  const float* x   = (const float*)d_in[0];
  const float* w0f = (const float*)d_in[1];
  const float* w1f = (const float*)d_in[3];
  const float* w2f = (const float*)d_in[5];
  const float* w3f = (const float*)d_in[7];  const float* b3f = (const float*)d_in[8];
  const float* w4f = (const float*)d_in[9];  const float* b4f = (const float*)d_in[10];
  const float* w5f = (const float*)d_in[11];
  const float* g0 = (const float*)d_in[13]; const float* be0 = (const float*)d_in[14];
  const float* g1 = (const float*)d_in[15]; const float* be1 = (const float*)d_in[16];
  const float* g2 = (const float*)d_in[17]; const float* be2 = (const float*)d_in[18];
  const float* g3 = (const float*)d_in[19]; const float* be3 = (const float*)d_in[20];

  const int M = in_sizes[0] / 3072;   // 16384
  char* w = (char*)d_ws;
  short* Abuf          = (short*)w;                          // 134217728
  unsigned char* X0p   = (unsigned char*)(w + 134217728);    // packed fp4
  unsigned char* Xbp   = (unsigned char*)(w + 184549376);    // packed fp4
  signed char* X3      = (signed char*)(w + 251658240);      // i8
  unsigned char* Ws0p  = (unsigned char*)(w + 255852544);
  unsigned char* Ws1p  = (unsigned char*)(w + 268435456);
  unsigned char* Ws2p  = (unsigned char*)(w + 285212672);
  signed char* Ws3 = (signed char*)(w + 286261248);
  signed char* Ws4 = (signed char*)(w + 286265344);
  signed char* Ws5 = (signed char*)(w + 286265600);
  int* A5          = (int*)(w + 286265856);
  ull* S0          = (ull*)(w + 286921216);
  ull* S1          = (ull*)(w + 286986752);
  ull* S2          = (ull*)(w + 287052288);
  ull* S5          = (ull*)(w + 287056384);
  float* P0m = (float*)(w + 287056640); float* P0s = (float*)(w + 287073024);
  float* P1m = (float*)(w + 287089408); float* P1s = (float*)(w + 287105792);
  float* P2m = (float*)(w + 287122176); float* P2s = (float*)(w + 287123200);
  float* P5m = (float*)(w + 287124224); float* P5s = (float*)(w + 287124288);

  hipMemsetAsync(w + 286921216, 0, 135424, stream);

  auto binp = [&](const float* src, unsigned char* dst, int n) {
    int n8 = n / 8;
    int grid = (n8 + 255) / 256; if (grid > 8192) grid = 8192;
    k_binp<<<grid, 256, 0, stream>>>((const float4*)src, (uint*)dst, n8);
  };
  binp(x,   X0p,  M * 3072);
  binp(w0f, Ws0p, 4096 * 3072);
  binp(w1f, Ws1p, 4096 * 4096);
  binp(w2f, Ws2p, 256 * 4096);
  k_bin<<<1, 64, 0, stream>>>((const float4*)w3f, (char4*)Ws3, 16 * 256 / 4);
  k_bin<<<1, 64, 0, stream>>>((const float4*)w4f, (char4*)Ws4, 16 * 16 / 4);
  k_bin<<<1, 40, 0, stream>>>((const float4*)w5f, (char4*)Ws5, 10 * 16 / 4);

  // Layer 0: [M,3072] x [4096,3072]^T  (stats fused into GEMM epilogue)
  k_bgemm2<3072, 4096><<<(4096 / 256) * (M / 256), 512, 0, stream>>>(X0p, Ws0p, Abuf, S0, M);
  k_finalize<<<16, 256, 0, stream>>>(S0, g0, M, 4096, P0m, P0s);
  k_signbn_pack<<<8192, 256, 0, stream>>>(Abuf, P0m, P0s, be0, (uint*)Xbp, M * 4096 / 8, 4095);

  // Layer 1: [M,4096] x [4096,4096]^T
  k_bgemm2<4096, 4096><<<(4096 / 256) * (M / 256), 512, 0, stream>>>(Xbp, Ws1p, Abuf, S1, M);
  k_finalize<<<16, 256, 0, stream>>>(S1, g1, M, 4096, P1m, P1s);
  k_signbn_pack<<<8192, 256, 0, stream>>>(Abuf, P1m, P1s, be1, (uint*)Xbp, M * 4096 / 8, 4095);

  // Layer 2: [M,4096] x [256,4096]^T  (output X3 stays i8 for the tail)
  k_bgemm<4096, 256><<<(256 / BN) * (M / BM), 256, 0, stream>>>(Xbp, Ws2p, Abuf, S2, M);
  k_finalize<<<1, 256, 0, stream>>>(S2, g2, M, 256, P2m, P2s);
  k_signbn<<<4096, 256, 0, stream>>>((const short4*)Abuf, P2m, P2s, be2, (char4*)X3, M * 256 / 4, 255);

  // Layers 3-5 fused + L5 stats
  k_tail<<<M / 16, 256, 0, stream>>>(X3, Ws3, Ws4, Ws5, b3f, b4f, A5, S5, M);
  k_finalize<<<1, 32, 0, stream>>>(S5, g3, M, 10, P5m, P5s);
  k_lsm<<<(M + 255) / 256, 256, 0, stream>>>(A5, P5m, P5s, be3, (float*)d_out, M);

  (void)n_in; (void)out_size; (void)ws_size;
}

// Round 11
// 482.022 us; speedup vs baseline: 4.6302x; 4.6302x over previous
//
#include <hip/hip_runtime.h>
#include <stdint.h>

typedef int v4i __attribute__((ext_vector_type(4)));
typedef int v8i __attribute__((ext_vector_type(8)));
typedef float v4f __attribute__((ext_vector_type(4)));
typedef short v8s __attribute__((ext_vector_type(8)));
typedef unsigned long long ull;
typedef unsigned int uint;

#define GLOAD16(g, l)                                                          \
  __builtin_amdgcn_global_load_lds(                                            \
      (const __attribute__((address_space(1))) void*)(g),                      \
      (__attribute__((address_space(3))) void*)(l), 16, 0, 0)

__device__ __forceinline__ signed char sgnf(float v) {
  return v > 0.f ? (signed char)1 : (v < 0.f ? (signed char)-1 : (signed char)0);
}
// fp4 e2m1 codes: +1.0 = 0x2, -1.0 = 0xA, 0.0 = 0x0
__device__ __forceinline__ uint nib(float v) {
  return v > 0.f ? 2u : (v < 0.f ? 10u : 0u);
}

// ---------------- binarize fp32 -> packed fp4 (2 elems/byte) ----------------
__global__ void k_binp(const float4* __restrict__ in, uint* __restrict__ out, int n8) {
  int i = blockIdx.x * blockDim.x + threadIdx.x;
  int stride = gridDim.x * blockDim.x;
  for (; i < n8; i += stride) {
    float4 a = in[i * 2], b = in[i * 2 + 1];
    out[i] = nib(a.x) | (nib(a.y) << 4) | (nib(a.z) << 8) | (nib(a.w) << 12) |
             (nib(b.x) << 16) | (nib(b.y) << 20) | (nib(b.z) << 24) | (nib(b.w) << 28);
  }
}

// ---------------- binarize the three tiny tail weights in ONE launch ----------
__global__ void k_bin3(const float* __restrict__ w3, const float* __restrict__ w4,
                       const float* __restrict__ w5, signed char* __restrict__ o3,
                       signed char* __restrict__ o4, signed char* __restrict__ o5) {
  int t = threadIdx.x;
#pragma unroll
  for (int i = t; i < 4096; i += 256) o3[i] = sgnf(w3[i]);
  if (t < 256) o4[t] = sgnf(w4[t]);
  if (t < 160) o5[t] = sgnf(w5[t]);
}

// ---- MX-fp4 binary GEMM (R6-verified): A[M,N] = X[M,K] * W[N,K]^T + stats ----
// 2-barrier m97 structure, single-buffer 32KB LDS, full unroll, natural block
// order (R5: bn % 8 partitions W panels across XCDs), nt output stores.
// ds_read lands DIRECTLY in the v8i fragment's low quad (high quad zeroed once)
// — removes the 64 v_mov/tile that drove VALUBusy to 35%.
#define BM 128
#define BN 128

template <int K, int N>
__global__ __launch_bounds__(256, 2) void k_bgemm(
    const unsigned char* __restrict__ X, const unsigned char* __restrict__ W,
    short* __restrict__ A, ull* __restrict__ S, int M)
{
  __shared__ __align__(16) unsigned char As[BM * 128];
  __shared__ __align__(16) unsigned char Bs[BN * 128];
  constexpr int Kb = K >> 1;             // packed row stride in bytes
  constexpr int NT = K / 256;            // 256 elements (128 B) per K-tile
  constexpr int NBX = N / BN;
  const int t = threadIdx.x;
  const int lane = t & 63;
  const int wave = t >> 6;
  const int wm = wave >> 1, wn = wave & 1;
  const int wg = blockIdx.x;             // natural order (R5 lesson)
  const int bm = (wg / NBX) * BM, bn = (wg % NBX) * BN;

  const int srow = lane >> 3;
  const int sslot = (lane & 7);

  const unsigned char* Xb0 = X + (size_t)bm * Kb;
  const unsigned char* Wb0 = W + (size_t)bn * Kb;

  v4f acc[4][4] = {};
  v8i a8[4], b8[4];
#pragma unroll
  for (int m = 0; m < 4; ++m) { a8[m] = (v8i)(0); b8[m] = (v8i)(0); }

  const unsigned char* gx[4];
  const unsigned char* gw[4];
  int ldsoff[4];
#pragma unroll
  for (int c = 0; c < 4; ++c) {
    int br = (wave * 4 + c) * 8;
    int row = br + srow;
    int ss = sslot ^ (row & 7);          // inverse swizzle on SOURCE
    gx[c] = Xb0 + (size_t)row * Kb + ss * 16;
    gw[c] = Wb0 + (size_t)row * Kb + ss * 16;
    ldsoff[c] = br * 128;
  }
  int aoff[4], boff[4];
#pragma unroll
  for (int m = 0; m < 4; ++m) {
    int arow = wm * 64 + m * 16 + (lane & 15);
    aoff[m] = arow * 128 + (((lane >> 4) ^ (arow & 7)) * 16);
    int brow = wn * 64 + m * 16 + (lane & 15);
    boff[m] = brow * 128 + (((lane >> 4) ^ (brow & 7)) * 16);
  }

#pragma unroll
  for (int tile = 0; tile < NT; ++tile) {
#pragma unroll
    for (int c = 0; c < 4; ++c) {
      GLOAD16(gx[c] + tile * 128, As + ldsoff[c]);
      GLOAD16(gw[c] + tile * 128, Bs + ldsoff[c]);
    }
    __syncthreads();                     // drains vmcnt + barrier
#pragma unroll
    for (int kk = 0; kk < 2; ++kk) {     // kk half: XOR 64 flips slot bit 2
#pragma unroll
      for (int m = 0; m < 4; ++m)
        *(v4i*)&a8[m] = *(const v4i*)(As + (aoff[m] ^ (kk << 6)));
#pragma unroll
      for (int n = 0; n < 4; ++n)
        *(v4i*)&b8[n] = *(const v4i*)(Bs + (boff[n] ^ (kk << 6)));
#pragma unroll
      for (int m = 0; m < 4; ++m)
#pragma unroll
        for (int n = 0; n < 4; ++n)
          acc[m][n] = __builtin_amdgcn_mfma_scale_f32_16x16x128_f8f6f4(
              a8[m], b8[n], acc[m][n], 4 /*fp4*/, 4 /*fp4*/,
              0, 0x7F7F7F7Fu, 0, 0x7F7F7F7Fu);
    }
    __syncthreads();                     // compute done before next overwrite
  }

  // C layout (verified): col = lane&15, row = (lane>>4)*4 + reg; nt stores
#pragma unroll
  for (int m = 0; m < 4; ++m) {
    int rbase = bm + wm * 64 + m * 16 + (lane >> 4) * 4;
#pragma unroll
    for (int n = 0; n < 4; ++n) {
      int col = bn + wn * 64 + n * 16 + (lane & 15);
#pragma unroll
      for (int r = 0; r < 4; ++r)
        __builtin_nontemporal_store((short)(int)acc[m][n][r],
                                    A + (size_t)(rbase + r) * N + col);
    }
  }

  // fused per-column stats (exact ints; deterministic integer atomics)
#pragma unroll
  for (int n = 0; n < 4; ++n) {
    int s = 0, q = 0;
#pragma unroll
    for (int m = 0; m < 4; ++m)
#pragma unroll
      for (int r = 0; r < 4; ++r) {
        int v = (int)acc[m][n][r];
        s += v; q += v * v;
      }
    s += __shfl_xor(s, 16); s += __shfl_xor(s, 32);
    q += __shfl_xor(q, 16); q += __shfl_xor(q, 32);
    if ((lane >> 4) == 0) {
      int col = bn + wn * 64 + n * 16 + (lane & 15);
      atomicAdd(&S[col], (ull)(long long)s);
      atomicAdd(&S[(size_t)N + col], (ull)(long long)q);
    }
  }
}

// ---------------- stats -> (mean, g*rsqrt(var+eps)) per column ----------------
__global__ void k_finalize(const ull* __restrict__ sums, const float* __restrict__ g,
                           int M, int N, float* __restrict__ meanf, float* __restrict__ sgf) {
  int j = blockIdx.x * blockDim.x + threadIdx.x;
  if (j >= N) return;
  double sum = (double)(long long)sums[j];
  double sumsq = (double)(long long)sums[N + j];
  double mean = sum / (double)M;
  double var = sumsq / (double)M - mean * mean;
  if (var < 0.0) var = 0.0;
  double inv = 1.0 / sqrt(var + 1e-5);
  meanf[j] = (float)mean;
  sgf[j] = (float)(inv * (double)g[j]);
}

// ---------------- sign(batchnorm(a)) -> packed fp4 (bias cancels under BN) ----
__global__ void k_signbn_pack(const short* __restrict__ A, const float* __restrict__ meanf,
                              const float* __restrict__ sgf, const float* __restrict__ be,
                              uint* __restrict__ Xp, int total8, int nmask) {
  int i = blockIdx.x * blockDim.x + threadIdx.x;
  int stride = gridDim.x * blockDim.x;
  for (; i < total8; i += stride) {
    v8s a = *(const v8s*)(A + (size_t)i * 8);
    int c0 = (i * 8) & nmask;
    uint b = 0;
#pragma unroll
    for (int j = 0; j < 8; ++j) {
      float z = ((float)a[j] - meanf[c0 + j]) * sgf[c0 + j] + be[c0 + j];
      b |= nib(z) << (4 * j);
    }
    Xp[i] = b;
  }
}

// ---------------- sign(batchnorm(a)) -> i8 (for the tail) ----------------
__global__ void k_signbn(const short4* __restrict__ A4, const float* __restrict__ meanf,
                         const float* __restrict__ sgf, const float* __restrict__ be,
                         char4* __restrict__ X4, int total4, int nmask) {
  int i = blockIdx.x * blockDim.x + threadIdx.x;
  int stride = gridDim.x * blockDim.x;
  for (; i < total4; i += stride) {
    short4 a = A4[i];
    int c0 = (i * 4) & nmask;
    char4 o;
    o.x = sgnf(((float)a.x - meanf[c0    ]) * sgf[c0    ] + be[c0    ]);
    o.y = sgnf(((float)a.y - meanf[c0 + 1]) * sgf[c0 + 1] + be[c0 + 1]);
    o.z = sgnf(((float)a.z - meanf[c0 + 2]) * sgf[c0 + 2] + be[c0 + 2]);
    o.w = sgnf(((float)a.w - meanf[c0 + 3]) * sgf[c0 + 3] + be[c0 + 3]);
    X4[i] = o;
  }
}

// ---------------- fused layers 3,4,5: X3[M,256] -> A5[M,10] + stats ----------------
__global__ __launch_bounds__(256) void k_tail(
    const signed char* __restrict__ X3, const signed char* __restrict__ W3,
    const signed char* __restrict__ W4, const signed char* __restrict__ W5,
    const float* __restrict__ b3, const float* __restrict__ b4,
    int* __restrict__ A5, ull* __restrict__ sums5, int M)
{
  __shared__ __align__(16) signed char sW3[16 * 256];
  __shared__ __align__(16) signed char sW4[256];
  __shared__ __align__(16) signed char sW5[160];
  __shared__ __align__(16) signed char sX[16 * 256];
  __shared__ signed char sH[16][16];
  __shared__ int bsum[10], bsq[10];
  int t = threadIdx.x;
  int rowBlock = blockIdx.x * 16;
  ((int4*)sW3)[t] = ((const int4*)W3)[t];
  ((int4*)sX)[t] = ((const int4*)(X3 + (size_t)rowBlock * 256))[t];
  if (t < 16) ((int4*)sW4)[t] = ((const int4*)W4)[t];
  if (t < 10) {
    ((int4*)sW5)[t] = ((const int4*)W5)[t];
    bsum[t] = 0; bsq[t] = 0;
  }
  __syncthreads();
  int r = t >> 4, j = t & 15;
  int d3 = 0;
#pragma unroll 8
  for (int k = 0; k < 256; ++k) d3 += (int)sX[r * 256 + k] * (int)sW3[j * 256 + k];
  sH[r][j] = sgnf((float)d3 + b3[j]);   // sign(hardtanh(z)) == sign(z)
  __syncthreads();
  int d4 = 0;
#pragma unroll
  for (int k = 0; k < 16; ++k) d4 += (int)sH[r][k] * (int)sW4[j * 16 + k];
  signed char x5 = sgnf((float)d4 + b4[j]);
  __syncthreads();
  sH[r][j] = x5;
  __syncthreads();
  if (j < 10) {
    int d5 = 0;
#pragma unroll
    for (int k = 0; k < 16; ++k) d5 += (int)sH[r][k] * (int)sW5[j * 16 + k];
    A5[(size_t)(rowBlock + r) * 10 + j] = d5;
    atomicAdd(&bsum[j], d5);
    atomicAdd(&bsq[j], d5 * d5);
  }
  __syncthreads();
  if (t < 10) {
    atomicAdd(&sums5[t], (ull)(long long)bsum[t]);
    atomicAdd(&sums5[10 + t], (ull)(long long)bsq[t]);
  }
}

// ---------------- final BN + log_softmax ----------------
__global__ void k_lsm(const int* __restrict__ A5, const float* __restrict__ meanf,
                      const float* __restrict__ sgf, const float* __restrict__ be,
                      float* __restrict__ out, int M) {
  int r = blockIdx.x * blockDim.x + threadIdx.x;
  if (r >= M) return;
  float tv[10]; float mx = -3.0e38f;
#pragma unroll
  for (int j = 0; j < 10; ++j) {
    tv[j] = ((float)A5[(size_t)r * 10 + j] - meanf[j]) * sgf[j] + be[j];
    mx = fmaxf(mx, tv[j]);
  }
  float s = 0.f;
#pragma unroll
  for (int j = 0; j < 10; ++j) s += expf(tv[j] - mx);
  float lse = mx + logf(s);
#pragma unroll
  for (int j = 0; j < 10; ++j) out[(size_t)r * 10 + j] = tv[j] - lse;
}

extern "C" void kernel_launch(void* const* d_in, const int* in_sizes, int n_in,
                              void* d_out, int out_size, void* d_ws, size_t ws_size,
                              hipStream_t stream) {
  const float* x   = (const float*)d_in[0];
  const float* w0f = (const float*)d_in[1];
  const float* w1f = (const float*)d_in[3];
  const float* w2f = (const float*)d_in[5];
  const float* w3f = (const float*)d_in[7];  const float* b3f = (const float*)d_in[8];
  const float* w4f = (const float*)d_in[9];  const float* b4f = (const float*)d_in[10];
  const float* w5f = (const float*)d_in[11];
  const float* g0 = (const float*)d_in[13]; const float* be0 = (const float*)d_in[14];
  const float* g1 = (const float*)d_in[15]; const float* be1 = (const float*)d_in[16];
  const float* g2 = (const float*)d_in[17]; const float* be2 = (const float*)d_in[18];
  const float* g3 = (const float*)d_in[19]; const float* be3 = (const float*)d_in[20];

  const int M = in_sizes[0] / 3072;   // 16384
  char* w = (char*)d_ws;
  short* Abuf          = (short*)w;                          // 134217728
  unsigned char* X0p   = (unsigned char*)(w + 134217728);    // packed fp4
  unsigned char* Xbp   = (unsigned char*)(w + 184549376);    // packed fp4
  signed char* X3      = (signed char*)(w + 251658240);      // i8
  unsigned char* Ws0p  = (unsigned char*)(w + 255852544);
  unsigned char* Ws1p  = (unsigned char*)(w + 268435456);
  unsigned char* Ws2p  = (unsigned char*)(w + 285212672);
  signed char* Ws3 = (signed char*)(w + 286261248);
  signed char* Ws4 = (signed char*)(w + 286265344);
  signed char* Ws5 = (signed char*)(w + 286265600);
  int* A5          = (int*)(w + 286265856);
  ull* S0          = (ull*)(w + 286921216);
  ull* S1          = (ull*)(w + 286986752);
  ull* S2          = (ull*)(w + 287052288);
  ull* S5          = (ull*)(w + 287056384);
  float* P0m = (float*)(w + 287056640); float* P0s = (float*)(w + 287073024);
  float* P1m = (float*)(w + 287089408); float* P1s = (float*)(w + 287105792);
  float* P2m = (float*)(w + 287122176); float* P2s = (float*)(w + 287123200);
  float* P5m = (float*)(w + 287124224); float* P5s = (float*)(w + 287124288);

  hipMemsetAsync(w + 286921216, 0, 135424, stream);

  auto binp = [&](const float* src, unsigned char* dst, int n) {
    int n8 = n / 8;
    int grid = (n8 + 255) / 256; if (grid > 8192) grid = 8192;
    k_binp<<<grid, 256, 0, stream>>>((const float4*)src, (uint*)dst, n8);
  };
  binp(x,   X0p,  M * 3072);
  binp(w0f, Ws0p, 4096 * 3072);
  binp(w1f, Ws1p, 4096 * 4096);
  binp(w2f, Ws2p, 256 * 4096);
  k_bin3<<<1, 256, 0, stream>>>(w3f, w4f, w5f, Ws3, Ws4, Ws5);

  // Layer 0: [M,3072] x [4096,3072]^T  (stats fused into GEMM epilogue)
  k_bgemm<3072, 4096><<<(4096 / BN) * (M / BM), 256, 0, stream>>>(X0p, Ws0p, Abuf, S0, M);
  k_finalize<<<16, 256, 0, stream>>>(S0, g0, M, 4096, P0m, P0s);
  k_signbn_pack<<<8192, 256, 0, stream>>>(Abuf, P0m, P0s, be0, (uint*)Xbp, M * 4096 / 8, 4095);

  // Layer 1: [M,4096] x [4096,4096]^T
  k_bgemm<4096, 4096><<<(4096 / BN) * (M / BM), 256, 0, stream>>>(Xbp, Ws1p, Abuf, S1, M);
  k_finalize<<<16, 256, 0, stream>>>(S1, g1, M, 4096, P1m, P1s);
  k_signbn_pack<<<8192, 256, 0, stream>>>(Abuf, P1m, P1s, be1, (uint*)Xbp, M * 4096 / 8, 4095);

  // Layer 2: [M,4096] x [256,4096]^T  (output X3 stays i8 for the tail)
  k_bgemm<4096, 256><<<(256 / BN) * (M / BM), 256, 0, stream>>>(Xbp, Ws2p, Abuf, S2, M);
  k_finalize<<<1, 256, 0, stream>>>(S2, g2, M, 256, P2m, P2s);
  k_signbn<<<4096, 256, 0, stream>>>((const short4*)Abuf, P2m, P2s, be2, (char4*)X3, M * 256 / 4, 255);

  // Layers 3-5 fused + L5 stats
  k_tail<<<M / 16, 256, 0, stream>>>(X3, Ws3, Ws4, Ws5, b3f, b4f, A5, S5, M);
  k_finalize<<<1, 32, 0, stream>>>(S5, g3, M, 10, P5m, P5s);
  k_lsm<<<(M + 255) / 256, 256, 0, stream>>>(A5, P5m, P5s, be3, (float*)d_out, M);

  (void)n_in; (void)out_size; (void)ws_size;
}

// Round 12
// 475.472 us; speedup vs baseline: 4.6940x; 1.0138x over previous
//
#include <hip/hip_runtime.h>
#include <stdint.h>

typedef int v4i __attribute__((ext_vector_type(4)));
typedef int v8i __attribute__((ext_vector_type(8)));
typedef float v4f __attribute__((ext_vector_type(4)));
typedef short v8s __attribute__((ext_vector_type(8)));
typedef unsigned long long ull;
typedef unsigned int uint;

#define GLOAD16(g, l)                                                          \
  __builtin_amdgcn_global_load_lds(                                            \
      (const __attribute__((address_space(1))) void*)(g),                      \
      (__attribute__((address_space(3))) void*)(l), 16, 0, 0)

__device__ __forceinline__ signed char sgnf(float v) {
  return v > 0.f ? (signed char)1 : (v < 0.f ? (signed char)-1 : (signed char)0);
}
// fp4 e2m1 codes: +1.0 = 0x2, -1.0 = 0xA, 0.0 = 0x0
__device__ __forceinline__ uint nib(float v) {
  return v > 0.f ? 2u : (v < 0.f ? 10u : 0u);
}

__device__ __forceinline__ void pack8(const float4* __restrict__ in,
                                      uint* __restrict__ out, int i) {
  float4 a = in[i * 2], b = in[i * 2 + 1];
  out[i] = nib(a.x) | (nib(a.y) << 4) | (nib(a.z) << 8) | (nib(a.w) << 12) |
           (nib(b.x) << 16) | (nib(b.y) << 20) | (nib(b.z) << 24) | (nib(b.w) << 28);
}

// ---- ONE launch binarizes everything: x,w0,w1,w2 -> packed fp4; w3,w4,w5 -> i8 ----
__global__ void k_binp_all(const float4* __restrict__ x,  uint* __restrict__ ox, int nx,
                           const float4* __restrict__ w0, uint* __restrict__ o0, int n0,
                           const float4* __restrict__ w1, uint* __restrict__ o1, int n1,
                           const float4* __restrict__ w2, uint* __restrict__ o2, int n2,
                           const float* __restrict__ w3, const float* __restrict__ w4,
                           const float* __restrict__ w5, signed char* __restrict__ o3,
                           signed char* __restrict__ o4, signed char* __restrict__ o5) {
  int gid = blockIdx.x * blockDim.x + threadIdx.x;
  int stride = gridDim.x * blockDim.x;
  for (int i = gid; i < nx; i += stride) pack8(x, ox, i);
  for (int i = gid; i < n0; i += stride) pack8(w0, o0, i);
  for (int i = gid; i < n1; i += stride) pack8(w1, o1, i);
  for (int i = gid; i < n2; i += stride) pack8(w2, o2, i);
  if (blockIdx.x == 0) {
    int t = threadIdx.x;
#pragma unroll
    for (int i = t; i < 4096; i += 256) o3[i] = sgnf(w3[i]);
    if (t < 256) o4[t] = sgnf(w4[t]);
    if (t < 160) o5[t] = sgnf(w5[t]);
  }
}

// ---- MX-fp4 binary GEMM (R6-verified structure): A[M,N] = X[M,K]*W[N,K]^T + stats ----
// 2-barrier m97 structure, single-buffer LDS, full unroll, natural block order
// (R5: bn%8 partitions W panels across XCDs), nt output stores.
// BNt template: 128 for big layers (bit-identical to verified R6 geometry),
// 64 for the N=256 layer (512 blocks instead of 256 -> full CU coverage).
#define BM 128

template <int K, int N, int BNt>
__global__ __launch_bounds__(256, 2) void k_bgemm(
    const unsigned char* __restrict__ X, const unsigned char* __restrict__ W,
    short* __restrict__ A, ull* __restrict__ S, int M)
{
  __shared__ __align__(16) unsigned char As[BM * 128];
  __shared__ __align__(16) unsigned char Bs[BNt * 128];
  constexpr int Kb = K >> 1;             // packed row stride in bytes
  constexpr int NT = K / 256;            // 256 elements (128 B) per K-tile
  constexpr int NBX = N / BNt;
  constexpr int NF = BNt / 32;           // per-wave n-fragments (wn in {0,1})
  constexpr int NCB = BNt / 32;          // B staging chunks per wave (8 rows each)
  const int t = threadIdx.x;
  const int lane = t & 63;
  const int wave = t >> 6;
  const int wm = wave >> 1, wn = wave & 1;
  const int wg = blockIdx.x;             // natural order (R5 lesson)
  const int bm = (wg / NBX) * BM, bn = (wg % NBX) * BNt;

  const int srow = lane >> 3;
  const int sslot = (lane & 7);

  const unsigned char* Xb0 = X + (size_t)bm * Kb;
  const unsigned char* Wb0 = W + (size_t)bn * Kb;

  v4f acc[4][NF] = {};
  v8i a8[4], b8[NF];
#pragma unroll
  for (int m = 0; m < 4; ++m) a8[m] = (v8i)(0);
#pragma unroll
  for (int n = 0; n < NF; ++n) b8[n] = (v8i)(0);

  const unsigned char* gx[4];
  int ldsoffA[4];
#pragma unroll
  for (int c = 0; c < 4; ++c) {
    int br = (wave * 4 + c) * 8;
    int row = br + srow;
    int ss = sslot ^ (row & 7);          // inverse swizzle on SOURCE
    gx[c] = Xb0 + (size_t)row * Kb + ss * 16;
    ldsoffA[c] = br * 128;
  }
  const unsigned char* gw[NCB];
  int ldsoffB[NCB];
#pragma unroll
  for (int c = 0; c < NCB; ++c) {
    int br = (wave * NCB + c) * 8;
    int row = br + srow;
    int ss = sslot ^ (row & 7);
    gw[c] = Wb0 + (size_t)row * Kb + ss * 16;
    ldsoffB[c] = br * 128;
  }
  int aoff[4], boff[NF];
#pragma unroll
  for (int m = 0; m < 4; ++m) {
    int arow = wm * 64 + m * 16 + (lane & 15);
    aoff[m] = arow * 128 + (((lane >> 4) ^ (arow & 7)) * 16);
  }
#pragma unroll
  for (int n = 0; n < NF; ++n) {
    int brow = wn * (BNt / 2) + n * 16 + (lane & 15);
    boff[n] = brow * 128 + (((lane >> 4) ^ (brow & 7)) * 16);
  }

#pragma unroll
  for (int tile = 0; tile < NT; ++tile) {
#pragma unroll
    for (int c = 0; c < 4; ++c)
      GLOAD16(gx[c] + tile * 128, As + ldsoffA[c]);
#pragma unroll
    for (int c = 0; c < NCB; ++c)
      GLOAD16(gw[c] + tile * 128, Bs + ldsoffB[c]);
    __syncthreads();                     // drains vmcnt + barrier
#pragma unroll
    for (int kk = 0; kk < 2; ++kk) {     // kk half: XOR 64 flips slot bit 2
#pragma unroll
      for (int m = 0; m < 4; ++m)
        *(v4i*)&a8[m] = *(const v4i*)(As + (aoff[m] ^ (kk << 6)));
#pragma unroll
      for (int n = 0; n < NF; ++n)
        *(v4i*)&b8[n] = *(const v4i*)(Bs + (boff[n] ^ (kk << 6)));
#pragma unroll
      for (int m = 0; m < 4; ++m)
#pragma unroll
        for (int n = 0; n < NF; ++n)
          acc[m][n] = __builtin_amdgcn_mfma_scale_f32_16x16x128_f8f6f4(
              a8[m], b8[n], acc[m][n], 4 /*fp4*/, 4 /*fp4*/,
              0, 0x7F7F7F7Fu, 0, 0x7F7F7F7Fu);
    }
    __syncthreads();                     // compute done before next overwrite
  }

  // C layout (verified): col = lane&15, row = (lane>>4)*4 + reg; nt stores
#pragma unroll
  for (int m = 0; m < 4; ++m) {
    int rbase = bm + wm * 64 + m * 16 + (lane >> 4) * 4;
#pragma unroll
    for (int n = 0; n < NF; ++n) {
      int col = bn + wn * (BNt / 2) + n * 16 + (lane & 15);
#pragma unroll
      for (int r = 0; r < 4; ++r)
        __builtin_nontemporal_store((short)(int)acc[m][n][r],
                                    A + (size_t)(rbase + r) * N + col);
    }
  }

  // fused per-column stats (exact ints; deterministic integer atomics)
#pragma unroll
  for (int n = 0; n < NF; ++n) {
    int s = 0, q = 0;
#pragma unroll
    for (int m = 0; m < 4; ++m)
#pragma unroll
      for (int r = 0; r < 4; ++r) {
        int v = (int)acc[m][n][r];
        s += v; q += v * v;
      }
    s += __shfl_xor(s, 16); s += __shfl_xor(s, 32);
    q += __shfl_xor(q, 16); q += __shfl_xor(q, 32);
    if ((lane >> 4) == 0) {
      int col = bn + wn * (BNt / 2) + n * 16 + (lane & 15);
      atomicAdd(&S[col], (ull)(long long)s);
      atomicAdd(&S[(size_t)N + col], (ull)(long long)q);
    }
  }
}

// ---------------- stats -> (mean, g*rsqrt(var+eps)) per column ----------------
__global__ void k_finalize(const ull* __restrict__ sums, const float* __restrict__ g,
                           int M, int N, float* __restrict__ meanf, float* __restrict__ sgf) {
  int j = blockIdx.x * blockDim.x + threadIdx.x;
  if (j >= N) return;
  double sum = (double)(long long)sums[j];
  double sumsq = (double)(long long)sums[N + j];
  double mean = sum / (double)M;
  double var = sumsq / (double)M - mean * mean;
  if (var < 0.0) var = 0.0;
  double inv = 1.0 / sqrt(var + 1e-5);
  meanf[j] = (float)mean;
  sgf[j] = (float)(inv * (double)g[j]);
}

// ---------------- sign(batchnorm(a)) -> packed fp4 (bias cancels under BN) ----
__global__ void k_signbn_pack(const short* __restrict__ A, const float* __restrict__ meanf,
                              const float* __restrict__ sgf, const float* __restrict__ be,
                              uint* __restrict__ Xp, int total8, int nmask) {
  int i = blockIdx.x * blockDim.x + threadIdx.x;
  int stride = gridDim.x * blockDim.x;
  for (; i < total8; i += stride) {
    v8s a = *(const v8s*)(A + (size_t)i * 8);
    int c0 = (i * 8) & nmask;
    uint b = 0;
#pragma unroll
    for (int j = 0; j < 8; ++j) {
      float z = ((float)a[j] - meanf[c0 + j]) * sgf[c0 + j] + be[c0 + j];
      b |= nib(z) << (4 * j);
    }
    Xp[i] = b;
  }
}

// ---------------- sign(batchnorm(a)) -> i8 (for the tail) ----------------
__global__ void k_signbn(const short4* __restrict__ A4, const float* __restrict__ meanf,
                         const float* __restrict__ sgf, const float* __restrict__ be,
                         char4* __restrict__ X4, int total4, int nmask) {
  int i = blockIdx.x * blockDim.x + threadIdx.x;
  int stride = gridDim.x * blockDim.x;
  for (; i < total4; i += stride) {
    short4 a = A4[i];
    int c0 = (i * 4) & nmask;
    char4 o;
    o.x = sgnf(((float)a.x - meanf[c0    ]) * sgf[c0    ] + be[c0    ]);
    o.y = sgnf(((float)a.y - meanf[c0 + 1]) * sgf[c0 + 1] + be[c0 + 1]);
    o.z = sgnf(((float)a.z - meanf[c0 + 2]) * sgf[c0 + 2] + be[c0 + 2]);
    o.w = sgnf(((float)a.w - meanf[c0 + 3]) * sgf[c0 + 3] + be[c0 + 3]);
    X4[i] = o;
  }
}

// ---------------- fused layers 3,4,5: X3[M,256] -> A5[M,10] + stats ----------------
__global__ __launch_bounds__(256) void k_tail(
    const signed char* __restrict__ X3, const signed char* __restrict__ W3,
    const signed char* __restrict__ W4, const signed char* __restrict__ W5,
    const float* __restrict__ b3, const float* __restrict__ b4,
    int* __restrict__ A5, ull* __restrict__ sums5, int M)
{
  __shared__ __align__(16) signed char sW3[16 * 256];
  __shared__ __align__(16) signed char sW4[256];
  __shared__ __align__(16) signed char sW5[160];
  __shared__ __align__(16) signed char sX[16 * 256];
  __shared__ signed char sH[16][16];
  __shared__ int bsum[10], bsq[10];
  int t = threadIdx.x;
  int rowBlock = blockIdx.x * 16;
  ((int4*)sW3)[t] = ((const int4*)W3)[t];
  ((int4*)sX)[t] = ((const int4*)(X3 + (size_t)rowBlock * 256))[t];
  if (t < 16) ((int4*)sW4)[t] = ((const int4*)W4)[t];
  if (t < 10) {
    ((int4*)sW5)[t] = ((const int4*)W5)[t];
    bsum[t] = 0; bsq[t] = 0;
  }
  __syncthreads();
  int r = t >> 4, j = t & 15;
  int d3 = 0;
#pragma unroll 8
  for (int k = 0; k < 256; ++k) d3 += (int)sX[r * 256 + k] * (int)sW3[j * 256 + k];
  sH[r][j] = sgnf((float)d3 + b3[j]);   // sign(hardtanh(z)) == sign(z)
  __syncthreads();
  int d4 = 0;
#pragma unroll
  for (int k = 0; k < 16; ++k) d4 += (int)sH[r][k] * (int)sW4[j * 16 + k];
  signed char x5 = sgnf((float)d4 + b4[j]);
  __syncthreads();
  sH[r][j] = x5;
  __syncthreads();
  if (j < 10) {
    int d5 = 0;
#pragma unroll
    for (int k = 0; k < 16; ++k) d5 += (int)sH[r][k] * (int)sW5[j * 16 + k];
    A5[(size_t)(rowBlock + r) * 10 + j] = d5;
    atomicAdd(&bsum[j], d5);
    atomicAdd(&bsq[j], d5 * d5);
  }
  __syncthreads();
  if (t < 10) {
    atomicAdd(&sums5[t], (ull)(long long)bsum[t]);
    atomicAdd(&sums5[10 + t], (ull)(long long)bsq[t]);
  }
}

// ---------------- final BN + log_softmax ----------------
__global__ void k_lsm(const int* __restrict__ A5, const float* __restrict__ meanf,
                      const float* __restrict__ sgf, const float* __restrict__ be,
                      float* __restrict__ out, int M) {
  int r = blockIdx.x * blockDim.x + threadIdx.x;
  if (r >= M) return;
  float tv[10]; float mx = -3.0e38f;
#pragma unroll
  for (int j = 0; j < 10; ++j) {
    tv[j] = ((float)A5[(size_t)r * 10 + j] - meanf[j]) * sgf[j] + be[j];
    mx = fmaxf(mx, tv[j]);
  }
  float s = 0.f;
#pragma unroll
  for (int j = 0; j < 10; ++j) s += expf(tv[j] - mx);
  float lse = mx + logf(s);
#pragma unroll
  for (int j = 0; j < 10; ++j) out[(size_t)r * 10 + j] = tv[j] - lse;
}

extern "C" void kernel_launch(void* const* d_in, const int* in_sizes, int n_in,
                              void* d_out, int out_size, void* d_ws, size_t ws_size,
                              hipStream_t stream) {
  const float* x   = (const float*)d_in[0];
  const float* w0f = (const float*)d_in[1];
  const float* w1f = (const float*)d_in[3];
  const float* w2f = (const float*)d_in[5];
  const float* w3f = (const float*)d_in[7];  const float* b3f = (const float*)d_in[8];
  const float* w4f = (const float*)d_in[9];  const float* b4f = (const float*)d_in[10];
  const float* w5f = (const float*)d_in[11];
  const float* g0 = (const float*)d_in[13]; const float* be0 = (const float*)d_in[14];
  const float* g1 = (const float*)d_in[15]; const float* be1 = (const float*)d_in[16];
  const float* g2 = (const float*)d_in[17]; const float* be2 = (const float*)d_in[18];
  const float* g3 = (const float*)d_in[19]; const float* be3 = (const float*)d_in[20];

  const int M = in_sizes[0] / 3072;   // 16384
  char* w = (char*)d_ws;
  short* Abuf          = (short*)w;                          // 134217728
  unsigned char* X0p   = (unsigned char*)(w + 134217728);    // packed fp4
  unsigned char* Xbp   = (unsigned char*)(w + 184549376);    // packed fp4
  signed char* X3      = (signed char*)(w + 251658240);      // i8
  unsigned char* Ws0p  = (unsigned char*)(w + 255852544);
  unsigned char* Ws1p  = (unsigned char*)(w + 268435456);
  unsigned char* Ws2p  = (unsigned char*)(w + 285212672);
  signed char* Ws3 = (signed char*)(w + 286261248);
  signed char* Ws4 = (signed char*)(w + 286265344);
  signed char* Ws5 = (signed char*)(w + 286265600);
  int* A5          = (int*)(w + 286265856);
  ull* S0          = (ull*)(w + 286921216);
  ull* S1          = (ull*)(w + 286986752);
  ull* S2          = (ull*)(w + 287052288);
  ull* S5          = (ull*)(w + 287056384);
  float* P0m = (float*)(w + 287056640); float* P0s = (float*)(w + 287073024);
  float* P1m = (float*)(w + 287089408); float* P1s = (float*)(w + 287105792);
  float* P2m = (float*)(w + 287122176); float* P2s = (float*)(w + 287123200);
  float* P5m = (float*)(w + 287124224); float* P5s = (float*)(w + 287124288);

  hipMemsetAsync(w + 286921216, 0, 135424, stream);

  // one launch: all binarize work
  k_binp_all<<<8192, 256, 0, stream>>>(
      (const float4*)x,   (uint*)X0p,  M * 3072 / 8,
      (const float4*)w0f, (uint*)Ws0p, 4096 * 3072 / 8,
      (const float4*)w1f, (uint*)Ws1p, 4096 * 4096 / 8,
      (const float4*)w2f, (uint*)Ws2p, 256 * 4096 / 8,
      w3f, w4f, w5f, Ws3, Ws4, Ws5);

  // Layer 0: [M,3072] x [4096,3072]^T  (stats fused into GEMM epilogue)
  k_bgemm<3072, 4096, 128><<<(4096 / 128) * (M / BM), 256, 0, stream>>>(X0p, Ws0p, Abuf, S0, M);
  k_finalize<<<16, 256, 0, stream>>>(S0, g0, M, 4096, P0m, P0s);
  k_signbn_pack<<<8192, 256, 0, stream>>>(Abuf, P0m, P0s, be0, (uint*)Xbp, M * 4096 / 8, 4095);

  // Layer 1: [M,4096] x [4096,4096]^T
  k_bgemm<4096, 4096, 128><<<(4096 / 128) * (M / BM), 256, 0, stream>>>(Xbp, Ws1p, Abuf, S1, M);
  k_finalize<<<16, 256, 0, stream>>>(S1, g1, M, 4096, P1m, P1s);
  k_signbn_pack<<<8192, 256, 0, stream>>>(Abuf, P1m, P1s, be1, (uint*)Xbp, M * 4096 / 8, 4095);

  // Layer 2: [M,4096] x [256,4096]^T  (BNt=64 -> 512 blocks, full CU coverage)
  k_bgemm<4096, 256, 64><<<(256 / 64) * (M / BM), 256, 0, stream>>>(Xbp, Ws2p, Abuf, S2, M);
  k_finalize<<<1, 256, 0, stream>>>(S2, g2, M, 256, P2m, P2s);
  k_signbn<<<4096, 256, 0, stream>>>((const short4*)Abuf, P2m, P2s, be2, (char4*)X3, M * 256 / 4, 255);

  // Layers 3-5 fused + L5 stats
  k_tail<<<M / 16, 256, 0, stream>>>(X3, Ws3, Ws4, Ws5, b3f, b4f, A5, S5, M);
  k_finalize<<<1, 32, 0, stream>>>(S5, g3, M, 10, P5m, P5s);
  k_lsm<<<(M + 255) / 256, 256, 0, stream>>>(A5, P5m, P5s, be3, (float*)d_out, M);

  (void)n_in; (void)out_size; (void)ws_size;
}